// Round 19
// baseline (141.083 us; speedup 1.0000x reference)
//
#include <hip/hip_runtime.h>
#include <hip/hip_bf16.h>

#define S_LEN 2048
#define NH 16
#define DH 64
#define DMODEL 1024
#define M_TOT 4096
#define LOG2E 1.44269504f

typedef __attribute__((ext_vector_type(8))) short bf16x8;
typedef __attribute__((ext_vector_type(4))) float f32x4;
typedef unsigned short u16;
typedef unsigned short us8 __attribute__((ext_vector_type(8)));

__device__ inline u16 f2bf(float f) {
    union { float f; unsigned u; } c; c.f = f;
    unsigned r = c.u + 0x7fffu + ((c.u >> 16) & 1u);
    return (u16)(r >> 16);
}

__device__ inline float exp2_raw(float x) {
    float r;
    asm volatile("v_exp_f32 %0, %1\n\ts_nop 0" : "=v"(r) : "v"(x));
    return r;
}

__device__ inline void load_lds16(const u16* g, u16* l) {
    __builtin_amdgcn_global_load_lds((const __attribute__((address_space(1))) void*)g,
                                     (__attribute__((address_space(3))) void*)l, 16, 0, 0);
}

__device__ inline us8 pack8(float4 a, float4 b) {
    us8 o;
    o[0] = f2bf(a.x); o[1] = f2bf(a.y); o[2] = f2bf(a.z); o[3] = f2bf(a.w);
    o[4] = f2bf(b.x); o[5] = f2bf(b.y); o[6] = f2bf(b.z); o[7] = f2bf(b.w);
    return o;
}

// ---------------------------------------------------------------------------
// Fused prep: [0,2048) hs->bf16; [2048,4096) 4 weights->bf16; [4096,4112) cm
// ---------------------------------------------------------------------------
__global__ __launch_bounds__(256) void prep(
    const float* __restrict__ hs,
    const float* __restrict__ w0, const float* __restrict__ w1,
    const float* __restrict__ w2, const float* __restrict__ w3,
    const float* __restrict__ mask,
    u16* __restrict__ hsb, u16* __restrict__ wbf,
    float* __restrict__ cm, u16* __restrict__ cmb)
{
    const int bid = blockIdx.x;
    if (bid < 2048) {
        const size_t i = ((size_t)bid * 256 + threadIdx.x) * 8;
        const float4 a = *(const float4*)(hs + i);
        const float4 b = *(const float4*)(hs + i + 4);
        *(us8*)(hsb + i) = pack8(a, b);
    } else if (bid < 4096) {
        const int z = (bid - 2048) >> 9;
        const float* src = (z == 0) ? w0 : (z == 1) ? w1 : (z == 2) ? w2 : w3;
        const size_t i = ((size_t)((bid - 2048) & 511) * 256 + threadIdx.x) * 8;
        const float4 a = *(const float4*)(src + i);
        const float4 b = *(const float4*)(src + i + 4);
        *(us8*)(wbf + (size_t)z * (DMODEL * DMODEL) + i) = pack8(a, b);
    } else {
        const int i = (bid - 4096) * 256 + threadIdx.x;
        const float c = exp2_raw(mask[i] * LOG2E);
        cm[i] = c;
        cmb[i] = f2bf(c);
    }
}

// ---------------------------------------------------------------------------
// QKV GEMM (r16-proven): both operands bf16 via global_load_lds, counted
// vmcnt(4), XCD co-tile remap, 128x128 tiles, 768 blocks.
// ---------------------------------------------------------------------------
__global__ __launch_bounds__(256) void gemm_qkv(
    const u16* __restrict__ hsb, const u16* __restrict__ wbf,
    const float* __restrict__ bq, const float* __restrict__ bk, const float* __restrict__ bv,
    const float* __restrict__ cm,
    u16* __restrict__ qb, u16* __restrict__ kb, u16* __restrict__ vT)
{
    __shared__ u16 lA[2][128 * 32];
    __shared__ u16 lB[2][128 * 32];
    const int tid = threadIdx.x, lane = tid & 63, w = tid >> 6;
    const int l15 = lane & 15, lg = lane >> 4;
    const int wr = w >> 1, wc = w & 1;

    const int flat = blockIdx.x + 8 * (blockIdx.y + 32 * blockIdx.z);
    const int xcd = flat & 7, l = flat >> 3;
    const int z = l >> 5, r = l & 31;
    const int n0 = ((xcd >> 2) * 4 + (r >> 3)) * 128;
    const int m0 = ((xcd & 3) * 8 + (r & 7)) * 128;

    const u16* Wp = wbf + (size_t)z * (DMODEL * DMODEL);
    const float* bias = (z == 0) ? bq : (z == 1) ? bk : bv;

    const u16 *aptr[2], *wptr[2]; int adst[2];
#pragma unroll
    for (int i = 0; i < 2; ++i) {
        const int rowb = (w * 2 + i) * 16;
        const int row = rowb + (lane >> 2);
        const int gc = (lane & 3) ^ ((row >> 1) & 3);
        aptr[i] = hsb + (size_t)(m0 + row) * DMODEL + gc * 8;
        wptr[i] = Wp + (size_t)(n0 + row) * DMODEL + gc * 8;
        adst[i] = rowb * 32;
    }
    int afo[4], bfo[4];
#pragma unroll
    for (int i = 0; i < 4; ++i) {
        const int rA = wr * 64 + i * 16 + l15;
        afo[i] = rA * 32 + ((lg ^ ((rA >> 1) & 3)) * 8);
        const int rB = wc * 64 + i * 16 + l15;
        bfo[i] = rB * 32 + ((lg ^ ((rB >> 1) & 3)) * 8);
    }

    f32x4 acc[4][4] = {};

#pragma unroll
    for (int i = 0; i < 2; ++i) {
        load_lds16(aptr[i], &lA[0][adst[i]]);
        load_lds16(wptr[i], &lB[0][adst[i]]);
    }

    int cur = 0;
    for (int t = 0; t < 32; ++t) {
        if (t < 31) {
#pragma unroll
            for (int i = 0; i < 2; ++i) {
                load_lds16(aptr[i] + (t + 1) * 32, &lA[cur ^ 1][adst[i]]);
                load_lds16(wptr[i] + (t + 1) * 32, &lB[cur ^ 1][adst[i]]);
            }
            asm volatile("s_waitcnt vmcnt(4)" ::: "memory");
        } else {
            asm volatile("s_waitcnt vmcnt(0)" ::: "memory");
        }
        __builtin_amdgcn_s_barrier();
        __builtin_amdgcn_sched_barrier(0);

        bf16x8 af[4], bfr[4];
#pragma unroll
        for (int i = 0; i < 4; ++i) {
            af[i] = *(bf16x8*)&lA[cur][afo[i]];
            bfr[i] = *(bf16x8*)&lB[cur][bfo[i]];
        }
        __builtin_amdgcn_s_setprio(1);
#pragma unroll
        for (int i = 0; i < 4; ++i)
#pragma unroll
            for (int j = 0; j < 4; ++j)
                acc[i][j] = __builtin_amdgcn_mfma_f32_16x16x32_bf16(af[i], bfr[j], acc[i][j], 0, 0, 0);
        __builtin_amdgcn_s_setprio(0);
        __builtin_amdgcn_s_barrier();
        cur ^= 1;
    }

    const float qsc = 0.125f * LOG2E;
    float bn[4];
#pragma unroll
    for (int j = 0; j < 4; ++j) bn[j] = bias[n0 + wc * 64 + j * 16 + l15];

#pragma unroll
    for (int i = 0; i < 4; ++i) {
        const int mbase = m0 + wr * 64 + i * 16 + lg * 4;
        if (z == 0) {
#pragma unroll
            for (int j = 0; j < 4; ++j) {
                const int n = n0 + wc * 64 + j * 16 + l15;
#pragma unroll
                for (int e = 0; e < 4; ++e)
                    qb[(size_t)(mbase + e) * DMODEL + n] = f2bf((acc[i][j][e] + bn[j]) * qsc);
            }
        } else if (z == 1) {
#pragma unroll
            for (int j = 0; j < 4; ++j) {
                const int n = n0 + wc * 64 + j * 16 + l15;
#pragma unroll
                for (int e = 0; e < 4; ++e)
                    kb[(size_t)(mbase + e) * DMODEL + n] = f2bf(acc[i][j][e] + bn[j]);
            }
        } else {
            const int bb = mbase >> 11, s = mbase & 2047;
            const float4 c4 = *(const float4*)&cm[bb * S_LEN + s];
#pragma unroll
            for (int j = 0; j < 4; ++j) {
                const int n = n0 + wc * 64 + j * 16 + l15;
                const int hh = n >> 6, dh = n & 63;
                ushort4 uv;
                uv.x = f2bf((acc[i][j][0] + bn[j]) * c4.x);
                uv.y = f2bf((acc[i][j][1] + bn[j]) * c4.y);
                uv.z = f2bf((acc[i][j][2] + bn[j]) * c4.z);
                uv.w = f2bf((acc[i][j][3] + bn[j]) * c4.w);
                *(ushort4*)&vT[((size_t)(bb * NH + hh) * DH + dh) * S_LEN + s] = uv;
            }
        }
    }
}

// ---------------------------------------------------------------------------
// O-projection, split-N (r16-proven): 128m x 64n, 512 blocks, vmcnt(3)
// ---------------------------------------------------------------------------
__global__ __launch_bounds__(256) void gemm_o(
    const u16* __restrict__ ctx, const u16* __restrict__ wobf,
    const float* __restrict__ bo, const float* __restrict__ resid,
    float* __restrict__ X)
{
    __shared__ u16 lA[2][128 * 32];
    __shared__ u16 lB[2][64 * 32];
    const int tid = threadIdx.x, lane = tid & 63, w = tid >> 6;
    const int l15 = lane & 15, lg = lane >> 4;

    const int flat = blockIdx.x;
    const int xcd = flat & 7, l = flat >> 3;
    const int n0 = ((xcd >> 2) * 8 + (l >> 3)) * 64;
    const int m0 = ((xcd & 3) * 8 + (l & 7)) * 128;

    const u16* aptr[2]; int adst[2];
#pragma unroll
    for (int i = 0; i < 2; ++i) {
        const int ck = i * 256 + tid;
        const int row = ck >> 2, slot = ck & 3;
        aptr[i] = ctx + (size_t)(m0 + row) * DMODEL + ((slot ^ ((row >> 1) & 3)) * 8);
        adst[i] = (i * 256 + w * 64) * 8;
    }
    const u16* wptr;
    int wdst;
    {
        const int row = tid >> 2, slot = tid & 3;
        wptr = wobf + (size_t)(n0 + row) * DMODEL + ((slot ^ ((row >> 1) & 3)) * 8);
        wdst = (w * 64) * 8;
    }
    int afo[2], bfo[4];
#pragma unroll
    for (int i = 0; i < 2; ++i) {
        const int rA = w * 32 + i * 16 + l15;
        afo[i] = rA * 32 + ((lg ^ ((rA >> 1) & 3)) * 8);
    }
#pragma unroll
    for (int j = 0; j < 4; ++j) {
        const int rB = j * 16 + l15;
        bfo[j] = rB * 32 + ((lg ^ ((rB >> 1) & 3)) * 8);
    }

    f32x4 acc[2][4] = {};

    load_lds16(aptr[0], &lA[0][adst[0]]);
    load_lds16(aptr[1], &lA[0][adst[1]]);
    load_lds16(wptr, &lB[0][wdst]);

    int cur = 0;
    for (int t = 0; t < 32; ++t) {
        if (t < 31) {
            load_lds16(aptr[0] + (t + 1) * 32, &lA[cur ^ 1][adst[0]]);
            load_lds16(aptr[1] + (t + 1) * 32, &lA[cur ^ 1][adst[1]]);
            load_lds16(wptr + (t + 1) * 32, &lB[cur ^ 1][wdst]);
            asm volatile("s_waitcnt vmcnt(3)" ::: "memory");
        } else {
            asm volatile("s_waitcnt vmcnt(0)" ::: "memory");
        }
        __builtin_amdgcn_s_barrier();
        __builtin_amdgcn_sched_barrier(0);

        bf16x8 af[2], bfr[4];
#pragma unroll
        for (int i = 0; i < 2; ++i)
            af[i] = *(bf16x8*)&lA[cur][afo[i]];
#pragma unroll
        for (int j = 0; j < 4; ++j)
            bfr[j] = *(bf16x8*)&lB[cur][bfo[j]];
        __builtin_amdgcn_s_setprio(1);
#pragma unroll
        for (int i = 0; i < 2; ++i)
#pragma unroll
            for (int j = 0; j < 4; ++j)
                acc[i][j] = __builtin_amdgcn_mfma_f32_16x16x32_bf16(af[i], bfr[j], acc[i][j], 0, 0, 0);
        __builtin_amdgcn_s_setprio(0);
        __builtin_amdgcn_s_barrier();
        cur ^= 1;
    }

#pragma unroll
    for (int i = 0; i < 2; ++i) {
#pragma unroll
        for (int j = 0; j < 4; ++j) {
            const int n = n0 + j * 16 + l15;
            const float bnj = bo[n];
#pragma unroll
            for (int e = 0; e < 4; ++e) {
                const int m = m0 + w * 32 + i * 16 + lg * 4 + e;
                X[(size_t)m * DMODEL + n] = acc[i][j][e] + bnj + resid[(size_t)m * DMODEL + n];
            }
        }
    }
}

// ---------------------------------------------------------------------------
// Flash attention, KVBLK=256: one vmcnt(16)+barrier-pair per 256 k-positions
// (8 iterations). 8 waves x 16 q-rows, LDS 144KB (1 block/CU), raw v_exp_f32.
// ---------------------------------------------------------------------------
__global__ __launch_bounds__(512, 2) void attn13(
    const u16* __restrict__ qg, const u16* __restrict__ kg,
    const u16* __restrict__ vTg, const u16* __restrict__ cmb,
    u16* __restrict__ ctx)
{
    __shared__ u16 Kl[2][256 * 64];   // [k-row][dh]  64 KB
    __shared__ u16 Vl[2][64 * 256];   // [dh][k]      64 KB
    __shared__ u16 Pl8[8][16 * 64];   // per-wave P   16 KB

    const int tid = threadIdx.x, lane = tid & 63, w = tid >> 6;
    const int bx = blockIdx.x;
    const int x = bx & 7, rest = bx >> 3;
    const int qt = rest & 15, g2 = rest >> 4;
    const int hb = g2 * 8 + x;
    const int h = hb & (NH - 1), b = hb >> 4;

    const int l15 = lane & 15, lg = lane >> 4;
    const int q0 = qt * 128 + w * 16;
    const size_t rowbase = (size_t)b * S_LEN * DMODEL + h * DH;
    const size_t vbase = (size_t)(b * NH + h) * DH * S_LEN;
    u16* Pw = Pl8[w];

    bf16x8 aq[2];
#pragma unroll
    for (int kf = 0; kf < 2; ++kf)
        aq[kf] = *(const bf16x8*)&qg[rowbase + (size_t)(q0 + l15) * DMODEL + kf * 32 + lg * 8];

    const int lx = l15 & 7;
    int kbase[2];
#pragma unroll
    for (int kf = 0; kf < 2; ++kf)
        kbase[kf] = l15 * 64 + (((kf * 4 + lg) ^ lx) * 8);
    int vb2[8];
#pragma unroll
    for (int kf2 = 0; kf2 < 8; ++kf2)
        vb2[kf2] = l15 * 256 + (((kf2 * 4 + lg) ^ lx) * 8);
    const int phi = l15 >> 3, plo = l15 & 7;

    // staging: 2048 16B-chunks each for K and V; 512 threads x 4 each
    size_t ksoff[4], vsoff[4];
    int ldst[4];
#pragma unroll
    for (int t = 0; t < 4; ++t) {
        const int ck = t * 512 + tid;
        const int krow = ck >> 3, kslot = ck & 7;
        ksoff[t] = (size_t)krow * DMODEL + ((kslot ^ (krow & 7)) * 8);
        const int vrow = ck >> 5, vslot = ck & 31;
        vsoff[t] = (size_t)vrow * S_LEN + ((vslot ^ (vrow & 7)) * 8);
        ldst[t] = (t * 512 + w * 64) * 8;
    }
    const u16* cmb_b = cmb + (size_t)b * S_LEN + lg * 8;

    f32x4 po[4] = {};
    f32x4 pol = {};

    // prologue: cf loads first, then DMA tile 0
    bf16x8 cf[8];
#pragma unroll
    for (int j = 0; j < 8; ++j)
        cf[j] = *(const bf16x8*)&cmb_b[j * 32];
    const u16* kp = kg + rowbase;
    const u16* vp = vTg + vbase;
#pragma unroll
    for (int t = 0; t < 4; ++t) {
        load_lds16(kp + ksoff[t], &Kl[0][ldst[t]]);
        load_lds16(vp + vsoff[t], &Vl[0][ldst[t]]);
    }
    kp += 256 * DMODEL; vp += 256;

    int cur = 0;
    for (int kt = 0; kt < S_LEN / 256; ++kt) {
        bf16x8 nx[8];
        if (kt + 1 < S_LEN / 256) {
#pragma unroll
            for (int j = 0; j < 8; ++j)
                nx[j] = *(const bf16x8*)&cmb_b[(kt + 1) * 256 + j * 32];
#pragma unroll
            for (int t = 0; t < 4; ++t) {
                load_lds16(kp + ksoff[t], &Kl[cur ^ 1][ldst[t]]);
                load_lds16(vp + vsoff[t], &Vl[cur ^ 1][ldst[t]]);
            }
            kp += 256 * DMODEL; vp += 256;
            asm volatile("s_waitcnt vmcnt(16)" ::: "memory");
        } else {
#pragma unroll
            for (int j = 0; j < 8; ++j) nx[j] = cf[j];
            asm volatile("s_waitcnt vmcnt(0)" ::: "memory");
        }
        __builtin_amdgcn_s_barrier();
        __builtin_amdgcn_sched_barrier(0);

#pragma unroll
        for (int h2 = 0; h2 < 4; ++h2) {
            // QK^T for this 64-k quarter: 8 MFMA
            f32x4 sa[4] = {};
            bf16x8 bkf[4][2];
#pragma unroll
            for (int nf = 0; nf < 4; ++nf)
#pragma unroll
                for (int kf = 0; kf < 2; ++kf)
                    bkf[nf][kf] = *(bf16x8*)&Kl[cur][(h2 * 4 + nf) * 1024 + kbase[kf]];
            __builtin_amdgcn_s_setprio(1);
#pragma unroll
            for (int nf = 0; nf < 4; ++nf)
#pragma unroll
                for (int kf = 0; kf < 2; ++kf)
                    sa[nf] = __builtin_amdgcn_mfma_f32_16x16x32_bf16(aq[kf], bkf[nf][kf], sa[nf], 0, 0, 0);
            __builtin_amdgcn_s_setprio(0);

            // softmax: p = 2^s -> bf16(trunc) -> wave-local P
#pragma unroll
            for (int e = 0; e < 4; ++e) {
                const int prow = lg * 4 + e;
                const int pbase = prow * 64 + plo;
                const int pxor = prow & 7;
#pragma unroll
                for (int nf = 0; nf < 4; ++nf) {
                    union { float f; unsigned u; } cv;
                    cv.f = exp2_raw(sa[nf][e]);
                    Pw[pbase + (((nf * 2 + phi) ^ pxor) * 8)] = (u16)(cv.u >> 16);
                }
            }

            // PV + c-weighted row-sum: 10 MFMA
#pragma unroll
            for (int j = 0; j < 2; ++j) {
                const int kf2 = h2 * 2 + j;
                bf16x8 ap = *(bf16x8*)&Pw[kbase[j]];
                bf16x8 bv[4];
#pragma unroll
                for (int df = 0; df < 4; ++df)
                    bv[df] = *(bf16x8*)&Vl[cur][df * 4096 + vb2[kf2]];
                const bf16x8 cfk = cf[kf2];
                __builtin_amdgcn_s_setprio(1);
#pragma unroll
                for (int df = 0; df < 4; ++df)
                    po[df] = __builtin_amdgcn_mfma_f32_16x16x32_bf16(ap, bv[df], po[df], 0, 0, 0);
                pol = __builtin_amdgcn_mfma_f32_16x16x32_bf16(ap, cfk, pol, 0, 0, 0);
                __builtin_amdgcn_s_setprio(0);
            }
        }
        __builtin_amdgcn_s_barrier();
#pragma unroll
        for (int j = 0; j < 8; ++j) cf[j] = nx[j];
        cur ^= 1;
    }

#pragma unroll
    for (int e = 0; e < 4; ++e) {
        const float inv = 1.0f / pol[e];
        const int qrow = q0 + lg * 4 + e;
#pragma unroll
        for (int df = 0; df < 4; ++df)
            ctx[((size_t)b * S_LEN + qrow) * DMODEL + h * DH + df * 16 + l15] = f2bf(po[df][e] * inv);
    }
}

// ---------------------------------------------------------------------------
// LayerNorm: reads X (ws), writes d_out
// ---------------------------------------------------------------------------
__global__ __launch_bounds__(256) void ln_kernel(
    const float* __restrict__ xin, float* __restrict__ y,
    const float* __restrict__ gamma, const float* __restrict__ beta)
{
    const int row = blockIdx.x;
    const int tid = threadIdx.x;
    float4 vv = *(const float4*)(xin + (size_t)row * DMODEL + tid * 4);
    float s = vv.x + vv.y + vv.z + vv.w;
    float s2 = vv.x * vv.x + vv.y * vv.y + vv.z * vv.z + vv.w * vv.w;
#pragma unroll
    for (int d = 1; d < 64; d <<= 1) { s += __shfl_xor(s, d); s2 += __shfl_xor(s2, d); }
    __shared__ float rs[4], rs2[4];
    if ((tid & 63) == 0) { rs[tid >> 6] = s; rs2[tid >> 6] = s2; }
    __syncthreads();
    s = rs[0] + rs[1] + rs[2] + rs[3];
    s2 = rs2[0] + rs2[1] + rs2[2] + rs2[3];
    const float mu = s * (1.f / DMODEL);
    const float var = s2 * (1.f / DMODEL) - mu * mu;
    const float inv = rsqrtf(var + 1e-5f);
    const float4 g = *(const float4*)(gamma + tid * 4);
    const float4 bt = *(const float4*)(beta + tid * 4);
    vv.x = (vv.x - mu) * inv * g.x + bt.x;
    vv.y = (vv.y - mu) * inv * g.y + bt.y;
    vv.z = (vv.z - mu) * inv * g.z + bt.z;
    vv.w = (vv.w - mu) * inv * g.w + bt.w;
    *(float4*)(y + (size_t)row * DMODEL + tid * 4) = vv;
}

extern "C" void kernel_launch(void* const* d_in, const int* in_sizes, int n_in,
                              void* d_out, int out_size, void* d_ws, size_t ws_size,
                              hipStream_t stream) {
    const float* hs    = (const float*)d_in[0];
    const float* mask  = (const float*)d_in[1];
    const float* Wq    = (const float*)d_in[2];
    const float* bq    = (const float*)d_in[3];
    const float* Wk    = (const float*)d_in[4];
    const float* bk    = (const float*)d_in[5];
    const float* Wv    = (const float*)d_in[6];
    const float* bv    = (const float*)d_in[7];
    const float* Wo    = (const float*)d_in[9];
    const float* bo    = (const float*)d_in[10];
    const float* gamma = (const float*)d_in[11];
    const float* beta  = (const float*)d_in[12];
    float* out = (float*)d_out;

    const size_t MN = (size_t)M_TOT * DMODEL;     // 4M elements
    const size_t WN = (size_t)DMODEL * DMODEL;    // 1M elements
    u16* qb      = (u16*)d_ws;
    u16* kb      = qb + MN;
    u16* vT      = kb + MN;
    u16* scratch = vT + MN;
    float* X     = (float*)d_ws;        // 16 MB over qb+kb (dead after attn)

    u16*  wbf = (u16*)out;
    float* cm = out + MN - 4096 - 2048;
    u16*  cmb = (u16*)(out + MN - 2048);

    dim3 blk(256);

    prep<<<dim3(4112), blk, 0, stream>>>(hs, Wq, Wk, Wv, Wo, mask,
                                         scratch, wbf, cm, cmb);
    gemm_qkv<<<dim3(8, 32, 3), blk, 0, stream>>>(
        scratch, wbf, bq, bk, bv, cm, qb, kb, vT);
    attn13<<<dim3(512), dim3(512), 0, stream>>>(qb, kb, vT, cmb, scratch);
    gemm_o<<<dim3(512), blk, 0, stream>>>(
        scratch, wbf + 3 * WN, bo, hs, X);
    ln_kernel<<<M_TOT, blk, 0, stream>>>(X, out, gamma, beta);
}

// Round 20
// 133.429 us; speedup vs baseline: 1.0574x; 1.0574x over previous
//
#include <hip/hip_runtime.h>
#include <hip/hip_bf16.h>

#define S_LEN 2048
#define NH 16
#define DH 64
#define DMODEL 1024
#define M_TOT 4096
#define LOG2E 1.44269504f

typedef __attribute__((ext_vector_type(8))) short bf16x8;
typedef __attribute__((ext_vector_type(4))) float f32x4;
typedef unsigned short u16;
typedef unsigned short us8 __attribute__((ext_vector_type(8)));

__device__ inline u16 f2bf(float f) {
    union { float f; unsigned u; } c; c.f = f;
    unsigned r = c.u + 0x7fffu + ((c.u >> 16) & 1u);
    return (u16)(r >> 16);
}

__device__ inline float exp2_raw(float x) {
    float r;
    asm volatile("v_exp_f32 %0, %1\n\ts_nop 0" : "=v"(r) : "v"(x));
    return r;
}

__device__ inline void load_lds16(const u16* g, u16* l) {
    __builtin_amdgcn_global_load_lds((const __attribute__((address_space(1))) void*)g,
                                     (__attribute__((address_space(3))) void*)l, 16, 0, 0);
}

__device__ inline us8 pack8(float4 a, float4 b) {
    us8 o;
    o[0] = f2bf(a.x); o[1] = f2bf(a.y); o[2] = f2bf(a.z); o[3] = f2bf(a.w);
    o[4] = f2bf(b.x); o[5] = f2bf(b.y); o[6] = f2bf(b.z); o[7] = f2bf(b.w);
    return o;
}

// ---------------------------------------------------------------------------
// Fused prep: [0,2048) hs->bf16; [2048,4096) 4 weights->bf16; [4096,4112) cm
// ---------------------------------------------------------------------------
__global__ __launch_bounds__(256) void prep(
    const float* __restrict__ hs,
    const float* __restrict__ w0, const float* __restrict__ w1,
    const float* __restrict__ w2, const float* __restrict__ w3,
    const float* __restrict__ mask,
    u16* __restrict__ hsb, u16* __restrict__ wbf,
    float* __restrict__ cm, u16* __restrict__ cmb)
{
    const int bid = blockIdx.x;
    if (bid < 2048) {
        const size_t i = ((size_t)bid * 256 + threadIdx.x) * 8;
        const float4 a = *(const float4*)(hs + i);
        const float4 b = *(const float4*)(hs + i + 4);
        *(us8*)(hsb + i) = pack8(a, b);
    } else if (bid < 4096) {
        const int z = (bid - 2048) >> 9;
        const float* src = (z == 0) ? w0 : (z == 1) ? w1 : (z == 2) ? w2 : w3;
        const size_t i = ((size_t)((bid - 2048) & 511) * 256 + threadIdx.x) * 8;
        const float4 a = *(const float4*)(src + i);
        const float4 b = *(const float4*)(src + i + 4);
        *(us8*)(wbf + (size_t)z * (DMODEL * DMODEL) + i) = pack8(a, b);
    } else {
        const int i = (bid - 4096) * 256 + threadIdx.x;
        const float c = exp2_raw(mask[i] * LOG2E);
        cm[i] = c;
        cmb[i] = f2bf(c);
    }
}

// ---------------------------------------------------------------------------
// QKV GEMM (r16-proven): both operands bf16 via global_load_lds, counted
// vmcnt(4), XCD co-tile remap, 128x128 tiles, 768 blocks.
// z=0: Q flat scaled; z=1: K flat; z=2: V*cm -> vT (B,H,DH,S)
// ---------------------------------------------------------------------------
__global__ __launch_bounds__(256) void gemm_qkv(
    const u16* __restrict__ hsb, const u16* __restrict__ wbf,
    const float* __restrict__ bq, const float* __restrict__ bk, const float* __restrict__ bv,
    const float* __restrict__ cm,
    u16* __restrict__ qb, u16* __restrict__ kb, u16* __restrict__ vT)
{
    __shared__ u16 lA[2][128 * 32];
    __shared__ u16 lB[2][128 * 32];
    const int tid = threadIdx.x, lane = tid & 63, w = tid >> 6;
    const int l15 = lane & 15, lg = lane >> 4;
    const int wr = w >> 1, wc = w & 1;

    const int flat = blockIdx.x + 8 * (blockIdx.y + 32 * blockIdx.z);
    const int xcd = flat & 7, l = flat >> 3;
    const int z = l >> 5, r = l & 31;
    const int n0 = ((xcd >> 2) * 4 + (r >> 3)) * 128;
    const int m0 = ((xcd & 3) * 8 + (r & 7)) * 128;

    const u16* Wp = wbf + (size_t)z * (DMODEL * DMODEL);
    const float* bias = (z == 0) ? bq : (z == 1) ? bk : bv;

    const u16 *aptr[2], *wptr[2]; int adst[2];
#pragma unroll
    for (int i = 0; i < 2; ++i) {
        const int rowb = (w * 2 + i) * 16;
        const int row = rowb + (lane >> 2);
        const int gc = (lane & 3) ^ ((row >> 1) & 3);
        aptr[i] = hsb + (size_t)(m0 + row) * DMODEL + gc * 8;
        wptr[i] = Wp + (size_t)(n0 + row) * DMODEL + gc * 8;
        adst[i] = rowb * 32;
    }
    int afo[4], bfo[4];
#pragma unroll
    for (int i = 0; i < 4; ++i) {
        const int rA = wr * 64 + i * 16 + l15;
        afo[i] = rA * 32 + ((lg ^ ((rA >> 1) & 3)) * 8);
        const int rB = wc * 64 + i * 16 + l15;
        bfo[i] = rB * 32 + ((lg ^ ((rB >> 1) & 3)) * 8);
    }

    f32x4 acc[4][4] = {};

#pragma unroll
    for (int i = 0; i < 2; ++i) {
        load_lds16(aptr[i], &lA[0][adst[i]]);
        load_lds16(wptr[i], &lB[0][adst[i]]);
    }

    int cur = 0;
    for (int t = 0; t < 32; ++t) {
        if (t < 31) {
#pragma unroll
            for (int i = 0; i < 2; ++i) {
                load_lds16(aptr[i] + (t + 1) * 32, &lA[cur ^ 1][adst[i]]);
                load_lds16(wptr[i] + (t + 1) * 32, &lB[cur ^ 1][adst[i]]);
            }
            asm volatile("s_waitcnt vmcnt(4)" ::: "memory");
        } else {
            asm volatile("s_waitcnt vmcnt(0)" ::: "memory");
        }
        __builtin_amdgcn_s_barrier();
        __builtin_amdgcn_sched_barrier(0);

        bf16x8 af[4], bfr[4];
#pragma unroll
        for (int i = 0; i < 4; ++i) {
            af[i] = *(bf16x8*)&lA[cur][afo[i]];
            bfr[i] = *(bf16x8*)&lB[cur][bfo[i]];
        }
        __builtin_amdgcn_s_setprio(1);
#pragma unroll
        for (int i = 0; i < 4; ++i)
#pragma unroll
            for (int j = 0; j < 4; ++j)
                acc[i][j] = __builtin_amdgcn_mfma_f32_16x16x32_bf16(af[i], bfr[j], acc[i][j], 0, 0, 0);
        __builtin_amdgcn_s_setprio(0);
        __builtin_amdgcn_s_barrier();
        cur ^= 1;
    }

    const float qsc = 0.125f * LOG2E;
    float bn[4];
#pragma unroll
    for (int j = 0; j < 4; ++j) bn[j] = bias[n0 + wc * 64 + j * 16 + l15];

#pragma unroll
    for (int i = 0; i < 4; ++i) {
        const int mbase = m0 + wr * 64 + i * 16 + lg * 4;
        if (z == 0) {
#pragma unroll
            for (int j = 0; j < 4; ++j) {
                const int n = n0 + wc * 64 + j * 16 + l15;
#pragma unroll
                for (int e = 0; e < 4; ++e)
                    qb[(size_t)(mbase + e) * DMODEL + n] = f2bf((acc[i][j][e] + bn[j]) * qsc);
            }
        } else if (z == 1) {
#pragma unroll
            for (int j = 0; j < 4; ++j) {
                const int n = n0 + wc * 64 + j * 16 + l15;
#pragma unroll
                for (int e = 0; e < 4; ++e)
                    kb[(size_t)(mbase + e) * DMODEL + n] = f2bf(acc[i][j][e] + bn[j]);
            }
        } else {
            const int bb = mbase >> 11, s = mbase & 2047;
            const float4 c4 = *(const float4*)&cm[bb * S_LEN + s];
#pragma unroll
            for (int j = 0; j < 4; ++j) {
                const int n = n0 + wc * 64 + j * 16 + l15;
                const int hh = n >> 6, dh = n & 63;
                ushort4 uv;
                uv.x = f2bf((acc[i][j][0] + bn[j]) * c4.x);
                uv.y = f2bf((acc[i][j][1] + bn[j]) * c4.y);
                uv.z = f2bf((acc[i][j][2] + bn[j]) * c4.z);
                uv.w = f2bf((acc[i][j][3] + bn[j]) * c4.w);
                *(ushort4*)&vT[((size_t)(bb * NH + hh) * DH + dh) * S_LEN + s] = uv;
            }
        }
    }
}

// ---------------------------------------------------------------------------
// O-projection, split-N (r16-proven): 128m x 64n, 512 blocks, vmcnt(3)
// ---------------------------------------------------------------------------
__global__ __launch_bounds__(256) void gemm_o(
    const u16* __restrict__ ctx, const u16* __restrict__ wobf,
    const float* __restrict__ bo, const float* __restrict__ resid,
    float* __restrict__ X)
{
    __shared__ u16 lA[2][128 * 32];
    __shared__ u16 lB[2][64 * 32];
    const int tid = threadIdx.x, lane = tid & 63, w = tid >> 6;
    const int l15 = lane & 15, lg = lane >> 4;

    const int flat = blockIdx.x;
    const int xcd = flat & 7, l = flat >> 3;
    const int n0 = ((xcd >> 2) * 8 + (l >> 3)) * 64;
    const int m0 = ((xcd & 3) * 8 + (l & 7)) * 128;

    const u16* aptr[2]; int adst[2];
#pragma unroll
    for (int i = 0; i < 2; ++i) {
        const int ck = i * 256 + tid;
        const int row = ck >> 2, slot = ck & 3;
        aptr[i] = ctx + (size_t)(m0 + row) * DMODEL + ((slot ^ ((row >> 1) & 3)) * 8);
        adst[i] = (i * 256 + w * 64) * 8;
    }
    const u16* wptr;
    int wdst;
    {
        const int row = tid >> 2, slot = tid & 3;
        wptr = wobf + (size_t)(n0 + row) * DMODEL + ((slot ^ ((row >> 1) & 3)) * 8);
        wdst = (w * 64) * 8;
    }
    int afo[2], bfo[4];
#pragma unroll
    for (int i = 0; i < 2; ++i) {
        const int rA = w * 32 + i * 16 + l15;
        afo[i] = rA * 32 + ((lg ^ ((rA >> 1) & 3)) * 8);
    }
#pragma unroll
    for (int j = 0; j < 4; ++j) {
        const int rB = j * 16 + l15;
        bfo[j] = rB * 32 + ((lg ^ ((rB >> 1) & 3)) * 8);
    }

    f32x4 acc[2][4] = {};

    load_lds16(aptr[0], &lA[0][adst[0]]);
    load_lds16(aptr[1], &lA[0][adst[1]]);
    load_lds16(wptr, &lB[0][wdst]);

    int cur = 0;
    for (int t = 0; t < 32; ++t) {
        if (t < 31) {
            load_lds16(aptr[0] + (t + 1) * 32, &lA[cur ^ 1][adst[0]]);
            load_lds16(aptr[1] + (t + 1) * 32, &lA[cur ^ 1][adst[1]]);
            load_lds16(wptr + (t + 1) * 32, &lB[cur ^ 1][wdst]);
            asm volatile("s_waitcnt vmcnt(3)" ::: "memory");
        } else {
            asm volatile("s_waitcnt vmcnt(0)" ::: "memory");
        }
        __builtin_amdgcn_s_barrier();
        __builtin_amdgcn_sched_barrier(0);

        bf16x8 af[2], bfr[4];
#pragma unroll
        for (int i = 0; i < 2; ++i)
            af[i] = *(bf16x8*)&lA[cur][afo[i]];
#pragma unroll
        for (int j = 0; j < 4; ++j)
            bfr[j] = *(bf16x8*)&lB[cur][bfo[j]];
        __builtin_amdgcn_s_setprio(1);
#pragma unroll
        for (int i = 0; i < 2; ++i)
#pragma unroll
            for (int j = 0; j < 4; ++j)
                acc[i][j] = __builtin_amdgcn_mfma_f32_16x16x32_bf16(af[i], bfr[j], acc[i][j], 0, 0, 0);
        __builtin_amdgcn_s_setprio(0);
        __builtin_amdgcn_s_barrier();
        cur ^= 1;
    }

#pragma unroll
    for (int i = 0; i < 2; ++i) {
#pragma unroll
        for (int j = 0; j < 4; ++j) {
            const int n = n0 + j * 16 + l15;
            const float bnj = bo[n];
#pragma unroll
            for (int e = 0; e < 4; ++e) {
                const int m = m0 + w * 32 + i * 16 + lg * 4 + e;
                X[(size_t)m * DMODEL + n] = acc[i][j][e] + bnj + resid[(size_t)m * DMODEL + n];
            }
        }
    }
}

// ---------------------------------------------------------------------------
// Flash attention (attn11, r16/r18-proven): 8 waves x 16 q-rows (512 threads),
// KVBLK=128, counted vmcnt(8), raw v_exp_f32, LDS 80KB, 16 waves/CU.
// ---------------------------------------------------------------------------
__global__ __launch_bounds__(512, 4) void attn11(
    const u16* __restrict__ qg, const u16* __restrict__ kg,
    const u16* __restrict__ vTg, const u16* __restrict__ cmb,
    u16* __restrict__ ctx)
{
    __shared__ u16 Kl[2][128 * 64];
    __shared__ u16 Vl[2][64 * 128];
    __shared__ u16 Pl8[8][16 * 64];

    const int tid = threadIdx.x, lane = tid & 63, w = tid >> 6;
    const int bx = blockIdx.x;
    const int x = bx & 7, rest = bx >> 3;
    const int qt = rest & 15, g2 = rest >> 4;
    const int hb = g2 * 8 + x;
    const int h = hb & (NH - 1), b = hb >> 4;

    const int l15 = lane & 15, lg = lane >> 4;
    const int q0 = qt * 128 + w * 16;
    const size_t rowbase = (size_t)b * S_LEN * DMODEL + h * DH;
    const size_t vbase = (size_t)(b * NH + h) * DH * S_LEN;
    u16* Pw = Pl8[w];

    bf16x8 aq[2];
#pragma unroll
    for (int kf = 0; kf < 2; ++kf)
        aq[kf] = *(const bf16x8*)&qg[rowbase + (size_t)(q0 + l15) * DMODEL + kf * 32 + lg * 8];

    const int lx = l15 & 7;
    int kbase[2];
#pragma unroll
    for (int kf = 0; kf < 2; ++kf)
        kbase[kf] = l15 * 64 + (((kf * 4 + lg) ^ lx) * 8);
    int vb2[4];
#pragma unroll
    for (int kf2 = 0; kf2 < 4; ++kf2)
        vb2[kf2] = l15 * 128 + (((kf2 * 4 + lg) ^ lx) * 8);
    const int phi = l15 >> 3, plo = l15 & 7;

    size_t ksoff[2], vsoff[2];
    int ldst[2];
#pragma unroll
    for (int t = 0; t < 2; ++t) {
        const int ck = t * 512 + tid;
        const int krow = ck >> 3, kslot = ck & 7;
        ksoff[t] = (size_t)krow * DMODEL + ((kslot ^ (krow & 7)) * 8);
        const int vrow = ck >> 4, vslot = ck & 15;
        vsoff[t] = (size_t)vrow * S_LEN + ((vslot ^ (vrow & 7)) * 8);
        ldst[t] = (t * 512 + w * 64) * 8;
    }
    const u16* cmb_b = cmb + (size_t)b * S_LEN + lg * 8;

    f32x4 po[4] = {};
    f32x4 pol = {};

    bf16x8 cf[4];
#pragma unroll
    for (int j = 0; j < 4; ++j)
        cf[j] = *(const bf16x8*)&cmb_b[j * 32];
    const u16* kp = kg + rowbase;
    const u16* vp = vTg + vbase;
#pragma unroll
    for (int t = 0; t < 2; ++t) {
        load_lds16(kp + ksoff[t], &Kl[0][ldst[t]]);
        load_lds16(vp + vsoff[t], &Vl[0][ldst[t]]);
    }
    kp += 128 * DMODEL; vp += 128;

    int cur = 0;
    for (int kt = 0; kt < S_LEN / 128; ++kt) {
        bf16x8 nx[4];
        if (kt + 1 < S_LEN / 128) {
#pragma unroll
            for (int j = 0; j < 4; ++j)
                nx[j] = *(const bf16x8*)&cmb_b[(kt + 1) * 128 + j * 32];
#pragma unroll
            for (int t = 0; t < 2; ++t) {
                load_lds16(kp + ksoff[t], &Kl[cur ^ 1][ldst[t]]);
                load_lds16(vp + vsoff[t], &Vl[cur ^ 1][ldst[t]]);
            }
            kp += 128 * DMODEL; vp += 128;
            asm volatile("s_waitcnt vmcnt(8)" ::: "memory");
        } else {
#pragma unroll
            for (int j = 0; j < 4; ++j) nx[j] = cf[j];
            asm volatile("s_waitcnt vmcnt(0)" ::: "memory");
        }
        __builtin_amdgcn_s_barrier();
        __builtin_amdgcn_sched_barrier(0);

#pragma unroll
        for (int h2 = 0; h2 < 2; ++h2) {
            f32x4 sa[4] = {};
            bf16x8 bkf[4][2];
#pragma unroll
            for (int nf = 0; nf < 4; ++nf)
#pragma unroll
                for (int kf = 0; kf < 2; ++kf)
                    bkf[nf][kf] = *(bf16x8*)&Kl[cur][(h2 * 4 + nf) * 1024 + kbase[kf]];
            __builtin_amdgcn_s_setprio(1);
#pragma unroll
            for (int nf = 0; nf < 4; ++nf)
#pragma unroll
                for (int kf = 0; kf < 2; ++kf)
                    sa[nf] = __builtin_amdgcn_mfma_f32_16x16x32_bf16(aq[kf], bkf[nf][kf], sa[nf], 0, 0, 0);
            __builtin_amdgcn_s_setprio(0);

#pragma unroll
            for (int e = 0; e < 4; ++e) {
                const int prow = lg * 4 + e;
                const int pbase = prow * 64 + plo;
                const int pxor = prow & 7;
#pragma unroll
                for (int nf = 0; nf < 4; ++nf) {
                    union { float f; unsigned u; } cv;
                    cv.f = exp2_raw(sa[nf][e]);
                    Pw[pbase + (((nf * 2 + phi) ^ pxor) * 8)] = (u16)(cv.u >> 16);
                }
            }

#pragma unroll
            for (int j = 0; j < 2; ++j) {
                const int kf2 = h2 * 2 + j;
                bf16x8 ap = *(bf16x8*)&Pw[kbase[j]];
                bf16x8 bv[4];
#pragma unroll
                for (int df = 0; df < 4; ++df)
                    bv[df] = *(bf16x8*)&Vl[cur][df * 2048 + vb2[kf2]];
                const bf16x8 cfk = cf[kf2];
                __builtin_amdgcn_s_setprio(1);
#pragma unroll
                for (int df = 0; df < 4; ++df)
                    po[df] = __builtin_amdgcn_mfma_f32_16x16x32_bf16(ap, bv[df], po[df], 0, 0, 0);
                pol = __builtin_amdgcn_mfma_f32_16x16x32_bf16(ap, cfk, pol, 0, 0, 0);
                __builtin_amdgcn_s_setprio(0);
            }
        }
        __builtin_amdgcn_s_barrier();
#pragma unroll
        for (int j = 0; j < 4; ++j) cf[j] = nx[j];
        cur ^= 1;
    }

#pragma unroll
    for (int e = 0; e < 4; ++e) {
        const float inv = 1.0f / pol[e];
        const int qrow = q0 + lg * 4 + e;
#pragma unroll
        for (int df = 0; df < 4; ++df)
            ctx[((size_t)b * S_LEN + qrow) * DMODEL + h * DH + df * 16 + l15] = f2bf(po[df][e] * inv);
    }
}

// ---------------------------------------------------------------------------
// LayerNorm: reads X (ws), writes d_out
// ---------------------------------------------------------------------------
__global__ __launch_bounds__(256) void ln_kernel(
    const float* __restrict__ xin, float* __restrict__ y,
    const float* __restrict__ gamma, const float* __restrict__ beta)
{
    const int row = blockIdx.x;
    const int tid = threadIdx.x;
    float4 vv = *(const float4*)(xin + (size_t)row * DMODEL + tid * 4);
    float s = vv.x + vv.y + vv.z + vv.w;
    float s2 = vv.x * vv.x + vv.y * vv.y + vv.z * vv.z + vv.w * vv.w;
#pragma unroll
    for (int d = 1; d < 64; d <<= 1) { s += __shfl_xor(s, d); s2 += __shfl_xor(s2, d); }
    __shared__ float rs[4], rs2[4];
    if ((tid & 63) == 0) { rs[tid >> 6] = s; rs2[tid >> 6] = s2; }
    __syncthreads();
    s = rs[0] + rs[1] + rs[2] + rs[3];
    s2 = rs2[0] + rs2[1] + rs2[2] + rs2[3];
    const float mu = s * (1.f / DMODEL);
    const float var = s2 * (1.f / DMODEL) - mu * mu;
    const float inv = rsqrtf(var + 1e-5f);
    const float4 g = *(const float4*)(gamma + tid * 4);
    const float4 bt = *(const float4*)(beta + tid * 4);
    vv.x = (vv.x - mu) * inv * g.x + bt.x;
    vv.y = (vv.y - mu) * inv * g.y + bt.y;
    vv.z = (vv.z - mu) * inv * g.z + bt.z;
    vv.w = (vv.w - mu) * inv * g.w + bt.w;
    *(float4*)(y + (size_t)row * DMODEL + tid * 4) = vv;
}

extern "C" void kernel_launch(void* const* d_in, const int* in_sizes, int n_in,
                              void* d_out, int out_size, void* d_ws, size_t ws_size,
                              hipStream_t stream) {
    const float* hs    = (const float*)d_in[0];
    const float* mask  = (const float*)d_in[1];
    const float* Wq    = (const float*)d_in[2];
    const float* bq    = (const float*)d_in[3];
    const float* Wk    = (const float*)d_in[4];
    const float* bk    = (const float*)d_in[5];
    const float* Wv    = (const float*)d_in[6];
    const float* bv    = (const float*)d_in[7];
    const float* Wo    = (const float*)d_in[9];
    const float* bo    = (const float*)d_in[10];
    const float* gamma = (const float*)d_in[11];
    const float* beta  = (const float*)d_in[12];
    float* out = (float*)d_out;

    const size_t MN = (size_t)M_TOT * DMODEL;     // 4M elements
    const size_t WN = (size_t)DMODEL * DMODEL;    // 1M elements
    u16* qb      = (u16*)d_ws;
    u16* kb      = qb + MN;
    u16* vT      = kb + MN;
    u16* scratch = vT + MN;
    float* X     = (float*)d_ws;        // 16 MB over qb+kb (dead after attn)

    u16*  wbf = (u16*)out;
    float* cm = out + MN - 4096 - 2048;
    u16*  cmb = (u16*)(out + MN - 2048);

    dim3 blk(256);

    prep<<<dim3(4112), blk, 0, stream>>>(hs, Wq, Wk, Wv, Wo, mask,
                                         scratch, wbf, cm, cmb);
    gemm_qkv<<<dim3(8, 32, 3), blk, 0, stream>>>(
        scratch, wbf, bq, bk, bv, cm, qb, kb, vT);
    attn11<<<dim3(512), dim3(512), 0, stream>>>(qb, kb, vT, cmb, scratch);
    gemm_o<<<dim3(512), blk, 0, stream>>>(
        scratch, wbf + 3 * WN, bo, hs, X);
    ln_kernel<<<M_TOT, blk, 0, stream>>>(X, out, gamma, beta);
}